// Round 5
// baseline (172.412 us; speedup 1.0000x reference)
//
#include <hip/hip_runtime.h>
#include <math.h>
#include <stdint.h>

#define M_TOTAL 16384
#define DDIM    4096
#define EXP     64

typedef __attribute__((ext_vector_type(8)))  short bf16x8;
typedef __attribute__((ext_vector_type(16))) float f32x16;

__device__ inline uint32_t fbits(float f){ union{float f;uint32_t u;}c; c.f=f; return c.u; }
__device__ inline float    bitsf(uint32_t u){ union{uint32_t u;float f;}c; c.u=u; return c.f; }
__device__ inline bf16x8   asfrag(uint4 t){ return __builtin_bit_cast(bf16x8, t); }

// ---------------------------------------------------------------------------
// W pre-pack: split w/nw into 3 bf16 planes (truncation split, exact to 2^-24)
// stored in MFMA-B-fragment-linear order:
//   word index = (((s*256 + ktile)*2 + nt)*3 + pl)*256 + lane*4 + j
//   lane = (e&31) + 32*((k>>3)&1), word j holds k-elems 2j,2j+1
// ---------------------------------------------------------------------------
__global__ __launch_bounds__(256) void wpack_prep(
    const float* __restrict__ w, const float* __restrict__ nw,
    uint32_t* __restrict__ wpack)
{
    const int t = blockIdx.x * 256 + threadIdx.x;     // 786432 words total
    const int jw   = t & 3;
    const int lane = (t >> 2) & 63;
    const int rest = t >> 8;                          // ((s*256+kt)*2+nt)*3+pl
    const int pl   = rest % 3;
    const int r2   = rest / 3;
    const int nt   = r2 & 1;
    const int kt   = (r2 >> 1) & 255;
    const int s    = r2 >> 9;

    const int k0 = kt * 16 + (lane >> 5) * 8 + 2 * jw;
    const int e  = nt * 32 + (lane & 31);
    const float* __restrict__ src = s ? nw : w;
    float f0 = src[(size_t)k0 * EXP + e];
    float f1 = src[(size_t)(k0 + 1) * EXP + e];
    uint32_t u0 = fbits(f0), u1 = fbits(f1);
    for (int l = 0; l < pl; ++l) {                    // peel to level pl
        f0 -= bitsf(u0 & 0xFFFF0000u);
        f1 -= bitsf(u1 & 0xFFFF0000u);
        u0 = fbits(f0); u1 = fbits(f1);
    }
    wpack[t] = (u0 >> 16) | (u1 & 0xFFFF0000u);       // [lo=elem2j, hi=elem2j+1]
}

// ---------------------------------------------------------------------------
// MFMA GEMM: part[kp][row][e] = sum over k-plane of (x@w + noise@nw)
// A now staged through LDS: coalesced global_load_lds (16 rows x 64B per issue,
// source slot pre-XOR-swizzled), transposed on the ds_read_b128 side.
// ---------------------------------------------------------------------------
template<int KSPLIT>
__global__ __launch_bounds__(256, 2) void router_mfma2(
    const float* __restrict__ x, const float* __restrict__ noise,
    const uint32_t* __restrict__ wpack, float* __restrict__ part)
{
    constexpr int KRANGE = DDIM / KSPLIT;   // k per plane
    constexpr int VPS    = KRANGE / 16;     // ksteps per slice
    constexpr int NU     = 2 * VPS;         // ksteps total (both slices)

    __shared__ float    Al[2][4096];        // 2 x 16 KB: [row 0..255][k-slot 0..3][4]
    __shared__ uint32_t Wl[2][1536];        // 2 x 6 KB : frag-linear (nt*768+pl*256)

    const int tid  = threadIdx.x;
    const int w_   = tid >> 6;
    const int lane = tid & 63;
    const int l31  = lane & 31;
    const int kh   = lane >> 5;             // k-half of the fragment

    const int rowBase = blockIdx.x * 256;
    const int kp      = blockIdx.y;

    f32x16 acc[2][2], macc[2][2];
#pragma unroll
    for (int a = 0; a < 2; ++a)
#pragma unroll
        for (int b = 0; b < 2; ++b)
#pragma unroll
            for (int i = 0; i < 16; ++i) { acc[a][b][i] = 0.f; macc[a][b][i] = 0.f; }

    // ---- stage A tile for kstep t into Al[buf]: 16 coalesced issues (4/wave)
    auto stageA = [&](int t, int buf) {
        const int s = t / VPS, v = t % VPS;
        const float* __restrict__ base = s ? noise : x;
        const int kAbs = kp * KRANGE + v * 16;
#pragma unroll
        for (int i = 0; i < 4; ++i) {
            const int rloc = w_ * 64 + 16 * i + (lane >> 2);
            const int sl   = (lane & 3) ^ ((rloc >> 1) & 3);   // pre-swizzled source slot
            const float* src = base + (size_t)(rowBase + rloc) * DDIM + kAbs + sl * 4;
            __builtin_amdgcn_global_load_lds(
                (const __attribute__((address_space(1))) uint32_t*)src,
                (__attribute__((address_space(3))) uint32_t*)(&Al[buf][(w_ * 64 + 16 * i) * 16 + lane * 4]),
                16, 0, 0);
        }
    };
    // ---- stage W frags for kstep t: 6 issues (waves 0-3: f=w_; waves 0-1: f=4+w_)
    auto stageW = [&](int t, int buf) {
        const int s = t / VPS, v = t % VPS;
        const int kt = kp * VPS + v;
        const uint32_t* gp = wpack + (size_t)(s * 256 + kt) * 1536;
        {
            const int f = w_;
            __builtin_amdgcn_global_load_lds(
                (const __attribute__((address_space(1))) uint32_t*)(gp + f * 256 + lane * 4),
                (__attribute__((address_space(3))) uint32_t*)(&Wl[buf][f * 256 + lane * 4]),
                16, 0, 0);
        }
        if (w_ < 2) {
            const int f = 4 + w_;
            __builtin_amdgcn_global_load_lds(
                (const __attribute__((address_space(1))) uint32_t*)(gp + f * 256 + lane * 4),
                (__attribute__((address_space(3))) uint32_t*)(&Wl[buf][f * 256 + lane * 4]),
                16, 0, 0);
        }
    };

    // prologue
    stageA(0, 0);
    stageW(0, 0);
    __syncthreads();                        // drains vmcnt: buffers 0 ready

    int buf = 0;
    for (int t = 0; t < NU; ++t) {
        if (t + 1 < NU) { stageA(t + 1, buf ^ 1); stageW(t + 1, buf ^ 1); }

        // ---- A fragments from LDS (swizzled read), split to 3 bf16 frags per mt
        uint32_t fa1[2][4], fa2[2][4], fa3[2][4];
#pragma unroll
        for (int mt = 0; mt < 2; ++mt) {
            const int rloc = w_ * 64 + mt * 32 + l31;
            const int swz  = (rloc >> 1) & 3;
            const float* p = &Al[buf][rloc * 16];
            const float4 a0 = *(const float4*)(p + (((kh * 2 + 0) ^ swz) * 4));
            const float4 a1 = *(const float4*)(p + (((kh * 2 + 1) ^ swz) * 4));
            const float in[8] = { a0.x, a0.y, a0.z, a0.w, a1.x, a1.y, a1.z, a1.w };
#pragma unroll
            for (int j = 0; j < 4; ++j) {
                const float a = in[2 * j], b = in[2 * j + 1];
                const uint32_t ua = fbits(a), ub = fbits(b);
                const uint32_t ha = ua & 0xFFFF0000u, hb = ub & 0xFFFF0000u;
                fa1[mt][j] = (ha >> 16) | hb;
                const float ra = a - bitsf(ha), rb = b - bitsf(hb);
                const uint32_t ha2 = fbits(ra) & 0xFFFF0000u, hb2 = fbits(rb) & 0xFFFF0000u;
                fa2[mt][j] = (ha2 >> 16) | hb2;
                const float sa = ra - bitsf(ha2), sb = rb - bitsf(hb2);
                fa3[mt][j] = (fbits(sa) >> 16) | (fbits(sb) & 0xFFFF0000u);
            }
        }

        const uint32_t* wbase = &Wl[buf][lane * 4];
#pragma unroll
        for (int nt = 0; nt < 2; ++nt) {
            const bf16x8 b1 = asfrag(*(const uint4*)(wbase + nt * 768));
            const bf16x8 b2 = asfrag(*(const uint4*)(wbase + nt * 768 + 256));
            const bf16x8 b3 = asfrag(*(const uint4*)(wbase + nt * 768 + 512));
#pragma unroll
            for (int mt = 0; mt < 2; ++mt) {
                const bf16x8 a1 = asfrag(*(const uint4*)fa1[mt]);
                const bf16x8 a2 = asfrag(*(const uint4*)fa2[mt]);
                const bf16x8 a3 = asfrag(*(const uint4*)fa3[mt]);
                f32x16 c = acc[mt][nt];
                c = __builtin_amdgcn_mfma_f32_32x32x16_bf16(a1, b3, c, 0, 0, 0);
                c = __builtin_amdgcn_mfma_f32_32x32x16_bf16(a3, b1, c, 0, 0, 0);
                c = __builtin_amdgcn_mfma_f32_32x32x16_bf16(a2, b2, c, 0, 0, 0);
                c = __builtin_amdgcn_mfma_f32_32x32x16_bf16(a1, b2, c, 0, 0, 0);
                c = __builtin_amdgcn_mfma_f32_32x32x16_bf16(a2, b1, c, 0, 0, 0);
                c = __builtin_amdgcn_mfma_f32_32x32x16_bf16(a1, b1, c, 0, 0, 0);
                acc[mt][nt] = c;
            }
        }

        // drain 64-k window into fp32 masters (keeps per-add magnitudes small)
        if ((t & 3) == 3) {
#pragma unroll
            for (int a = 0; a < 2; ++a)
#pragma unroll
                for (int b = 0; b < 2; ++b)
#pragma unroll
                    for (int i = 0; i < 16; ++i) { macc[a][b][i] += acc[a][b][i]; acc[a][b][i] = 0.f; }
        }

        __syncthreads();                    // next buffers staged (vmcnt drained)
        buf ^= 1;
    }

    // write plane; C/D layout (HW-verified): col=lane&31, row=(r&3)+8*(r>>2)+4*(lane>>5)
    float* __restrict__ out = part + (size_t)blockIdx.y * M_TOTAL * EXP;
#pragma unroll
    for (int mt = 0; mt < 2; ++mt)
#pragma unroll
        for (int nt = 0; nt < 2; ++nt)
#pragma unroll
            for (int r = 0; r < 16; ++r) {
                const int row = rowBase + w_ * 64 + mt * 32 + (r & 3) + 8 * (r >> 2) + 4 * kh;
                out[(size_t)row * EXP + nt * 32 + l31] = macc[mt][nt][r];
            }
}

// one wave per row: logits = f64 sum of planes; top-2 (jax tie-break: lower index
// wins); gates = 2-logit softmax == renormalized full softmax.
__global__ __launch_bounds__(256) void topk_epilogue3(
    const float* __restrict__ part, const int nplanes, float* __restrict__ outv)
{
    const int tid  = threadIdx.x;
    const int lane = tid & 63;
    const int row  = blockIdx.x * 4 + (tid >> 6);

    double sd = 0.0;
    for (int p = 0; p < nplanes; ++p)
        sd += (double)part[((size_t)p * M_TOTAL + row) * EXP + lane];
    const float logit = (float)sd;

    float v = logit; int idx = lane;
#pragma unroll
    for (int off = 32; off >= 1; off >>= 1) {
        const float vo = __shfl_xor(v, off, 64);
        const int   io = __shfl_xor(idx, off, 64);
        if (vo > v || (vo == v && io < idx)) { v = vo; idx = io; }
    }
    const float v1 = v; const int i1 = idx;

    float v2 = (lane == i1) ? -INFINITY : logit; int idx2 = lane;
#pragma unroll
    for (int off = 32; off >= 1; off >>= 1) {
        const float vo = __shfl_xor(v2, off, 64);
        const int   io = __shfl_xor(idx2, off, 64);
        if (vo > v2 || (vo == v2 && io < idx2)) { v2 = vo; idx2 = io; }
    }

    if (lane == 0) {
        const float e2 = expf(v2 - v1);       // <= 1
        const float g1 = 1.0f / (1.0f + e2);
        const float g2 = e2 * g1;
        outv[(size_t)row * 2 + 0] = g1;
        outv[(size_t)row * 2 + 1] = g2;
        outv[(size_t)2 * M_TOTAL + row * 2 + 0] = (float)i1;
        outv[(size_t)2 * M_TOTAL + row * 2 + 1] = (float)idx2;
    }
}

extern "C" void kernel_launch(void* const* d_in, const int* in_sizes, int n_in,
                              void* d_out, int out_size, void* d_ws, size_t ws_size,
                              hipStream_t stream)
{
    const float* x     = (const float*)d_in[0];
    const float* noise = (const float*)d_in[1];
    const float* w     = (const float*)d_in[2];
    const float* nw    = (const float*)d_in[3];
    // d_in[4] = top_k (==2), compile-time assumed

    const size_t plane_bytes = (size_t)M_TOTAL * EXP * sizeof(float);
    const size_t wpack_bytes = (size_t)786432 * 4;
    float* part = (float*)d_ws;

    if (ws_size >= 8 * plane_bytes + wpack_bytes) {
        uint32_t* wpack = (uint32_t*)((char*)d_ws + 8 * plane_bytes);
        wpack_prep<<<3072, 256, 0, stream>>>(w, nw, wpack);
        router_mfma2<8><<<dim3(64, 8), 256, 0, stream>>>(x, noise, wpack, part);
        topk_epilogue3<<<M_TOTAL / 4, 256, 0, stream>>>(part, 8, (float*)d_out);
    } else if (ws_size >= 4 * plane_bytes + wpack_bytes) {
        uint32_t* wpack = (uint32_t*)((char*)d_ws + 4 * plane_bytes);
        wpack_prep<<<3072, 256, 0, stream>>>(w, nw, wpack);
        router_mfma2<4><<<dim3(64, 4), 256, 0, stream>>>(x, noise, wpack, part);
        topk_epilogue3<<<M_TOTAL / 4, 256, 0, stream>>>(part, 4, (float*)d_out);
    } else {
        uint32_t* wpack = (uint32_t*)((char*)d_ws + 2 * plane_bytes);
        wpack_prep<<<3072, 256, 0, stream>>>(w, nw, wpack);
        router_mfma2<2><<<dim3(64, 2), 256, 0, stream>>>(x, noise, wpack, part);
        topk_epilogue3<<<M_TOTAL / 4, 256, 0, stream>>>(part, 2, (float*)d_out);
    }
}